// Round 1
// baseline (201.033 us; speedup 1.0000x reference)
//
#include <hip/hip_runtime.h>

// TriangleLinear: out[b][8191-r] = bias[r] + sum_{c>=max(0,r-4)} W_packed[off(r)+c-c0(r)] * x[b][c]
// Memory-bound on the 134.4 MB packed-weight stream (read exactly once).

constexpr int N = 8192;      // N_IN == N_OUT
constexpr int BATCH = 8;
constexpr int ROWS = 4;      // rows per block (shared x loads across rows in registers)
constexpr int THREADS = 256;

__global__ __launch_bounds__(THREADS, 4)
void tri_linear_kernel(const float* __restrict__ x,
                       const float* __restrict__ w,
                       const float* __restrict__ bias,
                       float* __restrict__ out) {
  const int t = threadIdx.x;
  const int r0 = blockIdx.x * ROWS;

  // Per-row triangular start column and packed-offset base (uniform -> SGPRs).
  int c0[ROWS];
  const float* wrow[ROWS];
#pragma unroll
  for (int i = 0; i < ROWS; ++i) {
    const int r = r0 + i;
    c0[i] = (r > 4) ? (r - 4) : 0;
    // off(r) = sum_{k<r} (8192 - max(0,k-4)); closed form, fits in int64 comfortably.
    long long off = (r <= 5)
        ? (long long)r * N
        : 40960LL + (long long)(r - 5) * (long long)(N + 4)
          - ((long long)r * (long long)(r - 1) / 2 - 10LL);
    wrow[i] = w + (off - (long long)c0[i]);   // wrow[i][c] valid for c in [c0[i], N)
  }
  const int cb0 = c0[0] & ~(THREADS - 1);     // c0[0] is the min c0 of this block's rows

  float acc[ROWS][BATCH];
#pragma unroll
  for (int i = 0; i < ROWS; ++i)
#pragma unroll
    for (int b = 0; b < BATCH; ++b) acc[i][b] = 0.0f;

  // Main loop: lane-contiguous columns -> perfectly coalesced weight dwords.
  // x rows are 256 KB total: L2-resident, re-read from L2 (~2x weight bytes).
  for (int cb = cb0; cb < N; cb += THREADS) {
    const int c = cb + t;                      // c < N always (cb multiple of 256)
    float xv[BATCH];
#pragma unroll
    for (int b = 0; b < BATCH; ++b) xv[b] = x[b * N + c];
#pragma unroll
    for (int i = 0; i < ROWS; ++i) {
      const float wv = (c >= c0[i]) ? wrow[i][c] : 0.0f;  // diagonal-tile predicate
#pragma unroll
      for (int b = 0; b < BATCH; ++b)
        acc[i][b] = fmaf(wv, xv[b], acc[i][b]);
    }
  }

  // Cross-thread reduction: 32 (row,batch) sums over 256 threads, two LDS stages.
  __shared__ float red[ROWS * BATCH][THREADS + 1];  // +1 pad: conflict-free columns
#pragma unroll
  for (int i = 0; i < ROWS; ++i)
#pragma unroll
    for (int b = 0; b < BATCH; ++b)
      red[i * BATCH + b][t] = acc[i][b];
  __syncthreads();

  const int rb = t & 31;   // which (row,batch)
  const int g  = t >> 5;   // which 32-chunk of threads
  float s = 0.0f;
#pragma unroll
  for (int j = 0; j < 32; ++j) s += red[rb][g * 32 + j];

  __shared__ float red2[ROWS * BATCH][9];    // pad 8->9
  red2[rb][g] = s;
  __syncthreads();

  if (t < ROWS * BATCH) {
    float total = 0.0f;
#pragma unroll
    for (int gg = 0; gg < 8; ++gg) total += red2[t][gg];
    const int i = t >> 3, b = t & 7;
    const int r = r0 + i;
    out[b * N + (N - 1 - r)] = total + bias[r];  // last-dim flip + bias
  }
}

extern "C" void kernel_launch(void* const* d_in, const int* in_sizes, int n_in,
                              void* d_out, int out_size, void* d_ws, size_t ws_size,
                              hipStream_t stream) {
  const float* x    = (const float*)d_in[0];  // [8, 8192]
  const float* w    = (const float*)d_in[1];  // [33591286] packed triangular
  const float* bias = (const float*)d_in[2];  // [8192]
  float* out = (float*)d_out;                 // [8, 8192]
  tri_linear_kernel<<<N / ROWS, THREADS, 0, stream>>>(x, w, bias, out);
}

// Round 2
// 196.429 us; speedup vs baseline: 1.0234x; 1.0234x over previous
//
#include <hip/hip_runtime.h>

// TriangleLinear: out[b][8191-r] = bias[r] + sum_{c>=max(0,r-4)} W_packed[...] * x[b][c]
// HBM-bound on the 134.4 MB packed-weight stream (read exactly once) => ~21 us floor.
// R1 post-mortem: 131.6 KB reduction LDS capped occupancy at 1 block/CU (1 wave/SIMD,
// no latency hiding) -> 201 us. Fix: 34 KB transposed reduction tile (4 blocks/CU),
// float4 x loads, nontemporal weight stream, edge-peeled predicate-free main loop.

constexpr int N = 8192;      // N_IN == N_OUT
constexpr int BATCH = 8;
constexpr int ROWS = 4;      // rows per block: x loads shared across rows in registers
constexpr int THREADS = 256;
constexpr int VEC = 4;       // columns per thread (float4 x loads)
constexpr int TILE = THREADS * VEC;  // 1024 columns per block-iteration

__global__ __launch_bounds__(THREADS, 4)
void tri_linear_kernel(const float* __restrict__ x,
                       const float* __restrict__ w,
                       const float* __restrict__ bias,
                       float* __restrict__ out) {
  const int t = threadIdx.x;
  const int r0 = blockIdx.x * ROWS;

  // Per-row triangular start column and packed-row base pointers (uniform -> SGPR).
  int c0[ROWS];
  const float* wrow[ROWS];
#pragma unroll
  for (int i = 0; i < ROWS; ++i) {
    const int r = r0 + i;
    c0[i] = (r > 4) ? (r - 4) : 0;
    // off(r) = 8192*r - (r-5)(r-4)/2 for r>=5, else 8192*r. (off(8192)=33,591,286 = nW)
    long long off = (r <= 5)
        ? (long long)r * N
        : (long long)r * N - ((long long)(r - 5) * (long long)(r - 4)) / 2;
    wrow[i] = w + (off - (long long)c0[i]);   // wrow[i][c] valid for c in [c0[i], N)
  }
  const int cbA = c0[0] & ~(TILE - 1);        // c0[0] == min c0 of this block's rows

  float acc[ROWS][BATCH];
#pragma unroll
  for (int i = 0; i < ROWS; ++i)
#pragma unroll
    for (int b = 0; b < BATCH; ++b) acc[i][b] = 0.0f;

  // ---- Edge tile [cbA, cbA+TILE): predicated on the triangular boundary ----
  {
    const int c = cbA + VEC * t;
    float4 xv[BATCH];
#pragma unroll
    for (int b = 0; b < BATCH; ++b)
      xv[b] = *(const float4*)(x + b * N + c);
#pragma unroll
    for (int i = 0; i < ROWS; ++i) {
#pragma unroll
      for (int j = 0; j < VEC; ++j) {
        const int cj = c + j;
        const float wv = (cj >= c0[i]) ? __builtin_nontemporal_load(wrow[i] + cj)
                                       : 0.0f;
        const float* xe;
#pragma unroll
        for (int b = 0; b < BATCH; ++b) {
          xe = reinterpret_cast<const float*>(&xv[b]);
          acc[i][b] = fmaf(wv, xe[j], acc[i][b]);
        }
      }
    }
  }

  // ---- Main loop: predicate-free, fully coalesced ----
  for (int cb = cbA + TILE; cb < N; cb += TILE) {
    const int c = cb + VEC * t;
    float4 xv[BATCH];
#pragma unroll
    for (int b = 0; b < BATCH; ++b)
      xv[b] = *(const float4*)(x + b * N + c);
    float wv[ROWS][VEC];
#pragma unroll
    for (int i = 0; i < ROWS; ++i)
#pragma unroll
      for (int j = 0; j < VEC; ++j)
        wv[i][j] = __builtin_nontemporal_load(wrow[i] + c + j);  // stream-once: skip L2 reuse
#pragma unroll
    for (int i = 0; i < ROWS; ++i)
#pragma unroll
      for (int j = 0; j < VEC; ++j) {
        const float* xe;
#pragma unroll
        for (int b = 0; b < BATCH; ++b) {
          xe = reinterpret_cast<const float*>(&xv[b]);
          acc[i][b] = fmaf(wv[i][j], xe[j], acc[i][b]);
        }
      }
  }

  // ---- Reduction: 32 (row,batch) sums over 256 threads, transposed LDS tile ----
  // red[256][33] = 33.8 KB (vs R1's 131.6 KB that killed occupancy). Pad 33 ->
  // write bank (t + s) % 32 (2-way, free) and read bank (k + s) % 32 with s
  // spanning 0..31 across the wave (2-way, free).
  __shared__ float red[THREADS][ROWS * BATCH + 1];
#pragma unroll
  for (int i = 0; i < ROWS; ++i)
#pragma unroll
    for (int b = 0; b < BATCH; ++b)
      red[t][i * BATCH + b] = acc[i][b];
  __syncthreads();

  const int s = t & 31;     // which (row,batch) sum
  const int part = t >> 5;  // which 32-thread chunk
  float p = 0.0f;
#pragma unroll
  for (int k = 0; k < 32; ++k) p += red[part * 32 + k][s];

  __shared__ float red2[32][9];
  red2[s][part] = p;
  __syncthreads();

  if (t < 32) {
    float total = 0.0f;
#pragma unroll
    for (int g = 0; g < 8; ++g) total += red2[t][g];
    const int i = t >> 3, b = t & 7;   // t == i*BATCH + b == s
    const int r = r0 + i;
    out[b * N + (N - 1 - r)] = total + bias[r];  // last-dim flip + bias
  }
}

extern "C" void kernel_launch(void* const* d_in, const int* in_sizes, int n_in,
                              void* d_out, int out_size, void* d_ws, size_t ws_size,
                              hipStream_t stream) {
  const float* x    = (const float*)d_in[0];  // [8, 8192]
  const float* w    = (const float*)d_in[1];  // [33591286] packed triangular
  const float* bias = (const float*)d_in[2];  // [8192]
  float* out = (float*)d_out;                 // [8, 8192]
  tri_linear_kernel<<<N / ROWS, THREADS, 0, stream>>>(x, w, bias, out);
}